// Round 3
// baseline (252.288 us; speedup 1.0000x reference)
//
#include <hip/hip_runtime.h>
#include <math.h>

typedef float f32x2 __attribute__((ext_vector_type(2)));
typedef float f32x4 __attribute__((ext_vector_type(4)));

namespace {
constexpr int L = 48;
constexpr int OCT = 8;                      // time steps per prefetch window
constexpr float LN2f = 0.69314718055994530942f;
}

// One wave per batch element (1024 waves = 1/SIMD). Lane i < 48 owns label i.
// Linear-domain recurrence with deferred integer shift Mi (log2 domain):
//   p[i] ~ 2^(score[i]*log2e - Mi);  E[i][j] = e^{trans[i][j]} (VGPR row)
//   s[i] = sum_j p[j]*E[i][j]   (12 broadcast ds_read_b128 + packed fp32 FMA)
//   p'   = s * g,  g = e^{h[b,t,i]} * rs  (h prefetched 8 steps ahead)
// Renorm every 4 steps: max sampled from 16 live labels (24..39) already in
// registers; scale rs = 2^-(ke-127) folded into BOTH next-step branches.
__global__ __launch_bounds__(64, 1)
void crf_fwd(const float* __restrict__ h,
             const float* __restrict__ mask,
             const float* __restrict__ trans,
             float* __restrict__ out, int T) {
  const int b = blockIdx.x;
  const int lane = threadIdx.x;
  const bool active = lane < L;
  const int safelane = active ? lane : 0;   // in-bounds addr for idle lanes

  __shared__ __align__(16) float p_lds[64];

  // E row for this lane as 24 packed pairs; idle lanes: 0 (kills their p)
  f32x2 Ep[L / 2];
  if (active) {
#pragma unroll
    for (int k = 0; k < L / 2; ++k) {
      Ep[k].x = __expf(trans[lane * L + 2 * k]);
      Ep[k].y = __expf(trans[lane * L + 2 * k + 1]);
    }
  } else {
#pragma unroll
    for (int k = 0; k < L / 2; ++k) Ep[k] = (f32x2){0.f, 0.f};
  }

  float p = (lane == 1) ? 1.0f : 0.0f;      // BOS_IDX = 1; e^NEG = 0 exactly
  p_lds[lane] = p;                          // 1 wave: in-order DS, no barriers
  int Mi = 0;                               // exact accumulated log2 shift
  float rs = 1.0f;                          // pending renorm scale

  const float* __restrict__ hb = h + (size_t)b * T * L;
  const float* __restrict__ mb = mask + (size_t)b * T;
  const int NOCT = T / OCT;

  // 8-deep register prefetch (coalesced per-lane h loads; mask scalarizes)
  float hf[OCT], mf[OCT];
#pragma unroll
  for (int k = 0; k < OCT; ++k) {
    hf[k] = hb[k * L + safelane];
    mf[k] = mb[k];
  }

  for (int oct = 0; oct < NOCT; ++oct) {
    float hn[OCT], mn[OCT];
    if (oct + 1 < NOCT) {                   // issue next window ~8 steps early
      const float* nb = hb + (size_t)(oct + 1) * OCT * L;
#pragma unroll
      for (int k = 0; k < OCT; ++k) {
        hn[k] = nb[k * L + safelane];       // always in-bounds
        mn[k] = mb[(oct + 1) * OCT + k];
      }
    } else {
#pragma unroll
      for (int k = 0; k < OCT; ++k) { hn[k] = 0.f; mn[k] = 1.f; }
    }

#pragma unroll
    for (int tt = 0; tt < OCT; ++tt) {
      const bool RENORM = ((tt & 3) == 3);  // constant in unrolled body
      float g  = __expf(hf[tt]) * rs;       // off critical path
      float pr = p * rs;                    // renorm-consistent masked carry
      rs = 1.0f;

      const f32x4* p4 = reinterpret_cast<const f32x4*>(p_lds);
      f32x4 w0 = p4[0], w1 = p4[1];
      f32x2 a0 = w0.xy * Ep[0], a1 = w0.zw * Ep[1];
      f32x2 a2 = w1.xy * Ep[2], a3 = w1.zw * Ep[3];
      f32x4 w6s = w0, w7s = w0, w8s = w0, w9s = w0;  // renorm samples
#pragma unroll
      for (int k = 2; k < 12; ++k) {
        f32x4 t = p4[k];
        if (k & 1) { a2 += t.xy * Ep[2 * k]; a3 += t.zw * Ep[2 * k + 1]; }
        else       { a0 += t.xy * Ep[2 * k]; a1 += t.zw * Ep[2 * k + 1]; }
        if (RENORM) {                       // keep labels 24..39 alive
          if (k == 6) w6s = t;
          if (k == 7) w7s = t;
          if (k == 8) w8s = t;
          if (k == 9) w9s = t;
        }
      }
      f32x2 sc = (a0 + a1) + (a2 + a3);
      float s = sc.x + sc.y;
      float pn = s * g;
      p = (mf[tt] > 0.5f) ? pn : pr;        // mask wave-uniform per (b,t)
      p_lds[lane] = p;                      // broadcast for next step

      if (RENORM) {                         // all-register, wave-uniform
        float ma = fmaxf(fmaxf(w6s.x, w6s.y), fmaxf(w6s.z, w6s.w));
        float mb2 = fmaxf(fmaxf(w7s.x, w7s.y), fmaxf(w7s.z, w7s.w));
        float mc = fmaxf(fmaxf(w8s.x, w8s.y), fmaxf(w8s.z, w8s.w));
        float md = fmaxf(fmaxf(w9s.x, w9s.y), fmaxf(w9s.z, w9s.w));
        float mx = fmaxf(fmaxf(ma, mb2), fmaxf(mc, md));
        unsigned bits = __float_as_uint(mx);
        int ke = (int)(bits >> 23) & 0xFF;
        bool ok = (ke > 0) && (ke < 255);   // skip if sample all-0 / inf
        rs = ok ? __uint_as_float((unsigned)(254 - ke) << 23) : 1.0f;
        Mi += ok ? (ke - 127) : 0;
      }
    }
#pragma unroll
    for (int k = 0; k < OCT; ++k) { hf[k] = hn[k]; mf[k] = mn[k]; }
  }

  // out[b] = ln2 * (Mi + log2(sum_i p_i)); idle/dead lanes hold p = 0
  float ps = p;
#pragma unroll
  for (int off = 32; off; off >>= 1) ps += __shfl_xor(ps, off, 64);
  if (lane == 0) out[b] = ((float)Mi + __log2f(ps)) * LN2f;
}

extern "C" void kernel_launch(void* const* d_in, const int* in_sizes, int n_in,
                              void* d_out, int out_size, void* d_ws, size_t ws_size,
                              hipStream_t stream) {
  const float* h     = (const float*)d_in[0];
  const float* mask  = (const float*)d_in[1];
  const float* trans = (const float*)d_in[2];
  float* out = (float*)d_out;
  const int B = out_size;                   // one output per chain
  const int T = in_sizes[1] / B;            // mask has B*T elements
  crf_fwd<<<B, 64, 0, stream>>>(h, mask, trans, out, T);
}

// Round 4
// 239.257 us; speedup vs baseline: 1.0545x; 1.0545x over previous
//
#include <hip/hip_runtime.h>
#include <math.h>

namespace {
constexpr int L = 48;
constexpr int OCT = 8;                      // time steps per prefetch window
constexpr float LN2f = 0.69314718055994530942f;
}

// One wave per batch element (1024 waves = 1 per SIMD on 256 CUs).
// Lane i < 48 owns label i. Linear-domain recurrence, deferred log2 shift Mi:
//   p[i] ~ 2^(score[i]*log2e - Mi);  E[i][j] = e^{trans[i][j]} (VGPR row)
//   s[i] = sum_j p[j]*E[i][j];  p' = s * g,  g = e^{h[b,t,i]} * rs
// Broadcast of p is 48x v_readlane -> SGPRs (no LDS round-trip in the loop;
// that round-trip was the round-2 bottleneck: VALUBusy 24%, ~690 cy/step).
// FMAs are v_fmac_f32 with SGPR src0. Renorm every 4 steps: max over the
// (non-negative) p bit patterns via SALU unsigned-max tree — co-issued, free.
__global__ __launch_bounds__(64, 1)
void crf_fwd(const float* __restrict__ h,
             const float* __restrict__ mask,
             const float* __restrict__ trans,
             float* __restrict__ out, int T) {
  const int b = blockIdx.x;
  const int lane = threadIdx.x;
  const bool active = lane < L;
  const int safelane = active ? lane : 0;   // in-bounds addr for idle lanes

  // E row for this lane; idle lanes get 0 (kills their state permanently)
  float E[L];
  if (active) {
#pragma unroll
    for (int j = 0; j < L; ++j) E[j] = __expf(trans[lane * L + j]);
  } else {
#pragma unroll
    for (int j = 0; j < L; ++j) E[j] = 0.0f;
  }

  float p = (lane == 1) ? 1.0f : 0.0f;      // BOS_IDX = 1; e^NEG = 0 exactly
  int Mi = 0;                               // accumulated log2 shift (uniform)
  float rs = 1.0f;                          // pending renorm scale (uniform)

  const float* __restrict__ hb = h + (size_t)b * T * L;
  const float* __restrict__ mb = mask + (size_t)b * T;
  const int NOCT = T / OCT;

  // 8-deep register prefetch of h (coalesced per-lane) and mask (uniform)
  float hf[OCT], mf[OCT];
#pragma unroll
  for (int k = 0; k < OCT; ++k) {
    hf[k] = hb[k * L + safelane];
    mf[k] = mb[k];
  }

  for (int oct = 0; oct < NOCT; ++oct) {
    float hn[OCT], mn[OCT];
    if (oct + 1 < NOCT) {                   // issue next window ~8 steps early
      const float* nb = hb + (size_t)(oct + 1) * OCT * L;
#pragma unroll
      for (int k = 0; k < OCT; ++k) {
        hn[k] = nb[k * L + safelane];       // always in-bounds
        mn[k] = mb[(oct + 1) * OCT + k];
      }
    } else {
#pragma unroll
      for (int k = 0; k < OCT; ++k) { hn[k] = 0.f; mn[k] = 1.f; }
    }

#pragma unroll
    for (int tt = 0; tt < OCT; ++tt) {
      const bool RENORM = ((tt & 3) == 3);  // constant in unrolled body
      float g  = __expf(hf[tt]) * rs;       // off critical path (hf old)
      float pr = p * rs;                    // renorm-consistent masked carry
      rs = 1.0f;

      // broadcast p: 48 readlanes -> SGPRs; matvec: 48 v_fmac (SGPR src0)
      const int pb = __float_as_int(p);
      float a0 = 0.f, a1 = 0.f, a2 = 0.f, a3 = 0.f;
      unsigned mx = 0u;
#pragma unroll
      for (int j = 0; j < L; j += 4) {
        const int r0 = __builtin_amdgcn_readlane(pb, j + 0);
        const int r1 = __builtin_amdgcn_readlane(pb, j + 1);
        const int r2 = __builtin_amdgcn_readlane(pb, j + 2);
        const int r3 = __builtin_amdgcn_readlane(pb, j + 3);
        a0 = fmaf(__int_as_float(r0), E[j + 0], a0);
        a1 = fmaf(__int_as_float(r1), E[j + 1], a1);
        a2 = fmaf(__int_as_float(r2), E[j + 2], a2);
        a3 = fmaf(__int_as_float(r3), E[j + 3], a3);
        if (RENORM) {                       // p >= 0: uint order == float order
          const unsigned u0 = (unsigned)r0, u1 = (unsigned)r1;
          const unsigned u2 = (unsigned)r2, u3 = (unsigned)r3;
          const unsigned m01 = u0 > u1 ? u0 : u1;
          const unsigned m23 = u2 > u3 ? u2 : u3;
          const unsigned m03 = m01 > m23 ? m01 : m23;
          mx = mx > m03 ? mx : m03;         // SALU s_max_u32 tree (uniform)
        }
      }
      const float s = (a0 + a1) + (a2 + a3);
      const float pn = s * g;
      p = (mf[tt] > 0.5f) ? pn : pr;        // mask is wave-uniform per (b,t)

      if (RENORM) {                         // all-scalar, wave-uniform
        const int ke = (int)(mx >> 23);
        const bool ok = (ke > 0) && (ke < 255);
        rs = ok ? __uint_as_float((unsigned)(254 - ke) << 23) : 1.0f;
        Mi += ok ? (ke - 127) : 0;
      }
    }
#pragma unroll
    for (int k = 0; k < OCT; ++k) { hf[k] = hn[k]; mf[k] = mn[k]; }
  }

  // out[b] = ln2 * (Mi + log2(sum_i p_i)); idle/dead lanes hold p = 0
  float ps = p;
#pragma unroll
  for (int off = 32; off; off >>= 1) ps += __shfl_xor(ps, off, 64);
  if (lane == 0) out[b] = ((float)Mi + __log2f(ps)) * LN2f;
}

extern "C" void kernel_launch(void* const* d_in, const int* in_sizes, int n_in,
                              void* d_out, int out_size, void* d_ws, size_t ws_size,
                              hipStream_t stream) {
  const float* h     = (const float*)d_in[0];
  const float* mask  = (const float*)d_in[1];
  const float* trans = (const float*)d_in[2];
  float* out = (float*)d_out;
  const int B = out_size;                   // one output per chain
  const int T = in_sizes[1] / B;            // mask has B*T elements
  crf_fwd<<<B, 64, 0, stream>>>(h, mask, trans, out, T);
}

// Round 5
// 222.699 us; speedup vs baseline: 1.1329x; 1.0744x over previous
//
#include <hip/hip_runtime.h>
#include <math.h>

namespace {
constexpr int L = 48;
constexpr int OCT = 8;                      // time steps per prefetch window
constexpr float LN2f = 0.69314718055994530942f;
}

// Split the linear recurrence at T/2:
//   out = ln( 1^T [prod_{t=T-1..0} D_t E] e_BOS ),  D_t = diag(e^{h_t})
// Wave 0 (fwd):  p <- (E p) * g_t          for t = 0 .. S-1,   p0 = e_BOS
// Wave 1 (bwd):  q <- E^T (g_t (*) q)      for t = T-1 .. S,   q0 = 1
// combine: out = ln2 * (Mi_f + Mi_b + log2(sum_i p_i q_i)).
// Each wave: lane owns one label; broadcast via 48x v_readlane -> SGPR;
// 48x v_fmac with SGPR src0. Renorm every 4 steps: SALU unsigned-max over
// the broadcast bit patterns (p >= 0), scale folded into next step's g.
// 2 waves/SIMD now co-issue, filling the ~300 cy/step stall seen in round 3.
template<bool BWD>
__device__ __forceinline__ float half_pass(
    const float* __restrict__ hb, const float* __restrict__ mb,
    const float* __restrict__ trans, int T, int S, int lane,
    int& Mi_out, float& rs_out) {
  const bool active = lane < L;
  const int safelane = active ? lane : 0;

  // fwd: row lane of E;  bwd: column lane of E (i.e. row of E^T)
  float E[L];
  if (active) {
#pragma unroll
    for (int j = 0; j < L; ++j)
      E[j] = __expf(trans[BWD ? (j * L + lane) : (lane * L + j)]);
  } else {
#pragma unroll
    for (int j = 0; j < L; ++j) E[j] = 0.0f;
  }

  float p = BWD ? (active ? 1.0f : 0.0f)     // ones vector
                : ((lane == 1) ? 1.0f : 0.0f); // e_BOS; e^NEG = 0 exactly
  int Mi = 0;                                // accumulated log2 shift
  float rs = 1.0f;                           // pending renorm scale

  const int NOCT = S / OCT;

  float hf[OCT], mf[OCT];
#pragma unroll
  for (int k = 0; k < OCT; ++k) {
    const int t = BWD ? (T - 1 - k) : k;
    hf[k] = hb[t * L + safelane];
    mf[k] = mb[t];
  }

  for (int oct = 0; oct < NOCT; ++oct) {
    float hn[OCT], mn[OCT];
    if (oct + 1 < NOCT) {                    // issue next window 8 steps early
#pragma unroll
      for (int k = 0; k < OCT; ++k) {
        const int s = (oct + 1) * OCT + k;
        const int t = BWD ? (T - 1 - s) : s;
        hn[k] = hb[t * L + safelane];
        mn[k] = mb[t];
      }
    } else {
#pragma unroll
      for (int k = 0; k < OCT; ++k) { hn[k] = 0.f; mn[k] = 1.f; }
    }

#pragma unroll
    for (int tt = 0; tt < OCT; ++tt) {
      const bool RENORM = ((tt & 3) == 3);   // constant in unrolled body
      const float g = __expf(hf[tt]) * rs;   // exp off critical path
      const float pr = p * rs;               // masked carry (rs applied once)
      rs = 1.0f;

      // broadcast value: fwd -> p ; bwd -> g (*) q  (diag applied pre-matvec)
      const float bv = BWD ? (p * g) : p;
      const int pb = __float_as_int(bv);
      float a0 = 0.f, a1 = 0.f, a2 = 0.f, a3 = 0.f;
      unsigned mx = 0u;
#pragma unroll
      for (int j = 0; j < L; j += 4) {
        const int r0 = __builtin_amdgcn_readlane(pb, j + 0);
        const int r1 = __builtin_amdgcn_readlane(pb, j + 1);
        const int r2 = __builtin_amdgcn_readlane(pb, j + 2);
        const int r3 = __builtin_amdgcn_readlane(pb, j + 3);
        a0 = fmaf(__int_as_float(r0), E[j + 0], a0);
        a1 = fmaf(__int_as_float(r1), E[j + 1], a1);
        a2 = fmaf(__int_as_float(r2), E[j + 2], a2);
        a3 = fmaf(__int_as_float(r3), E[j + 3], a3);
        if (RENORM) {                        // p >= 0: uint order == float
          const unsigned u0 = (unsigned)r0, u1 = (unsigned)r1;
          const unsigned u2 = (unsigned)r2, u3 = (unsigned)r3;
          const unsigned m01 = u0 > u1 ? u0 : u1;
          const unsigned m23 = u2 > u3 ? u2 : u3;
          const unsigned m03 = m01 > m23 ? m01 : m23;
          mx = mx > m03 ? mx : m03;          // SALU s_max_u32 tree
        }
      }
      const float s = (a0 + a1) + (a2 + a3);
      const float pn = BWD ? s : s * g;
      p = (mf[tt] > 0.5f) ? pn : pr;         // mask wave-uniform per (b,t)

      if (RENORM) {                          // all-scalar, wave-uniform
        const int ke = (int)(mx >> 23);
        const bool ok = (ke > 0) && (ke < 255);
        rs = ok ? __uint_as_float((unsigned)(254 - ke) << 23) : 1.0f;
        Mi += ok ? (ke - 127) : 0;
      }
    }
#pragma unroll
    for (int k = 0; k < OCT; ++k) { hf[k] = hn[k]; mf[k] = mn[k]; }
  }
  Mi_out = Mi;
  rs_out = rs;                               // pending scale — apply at exit!
  return p;
}

__global__ __launch_bounds__(128, 2)
void crf_fwd(const float* __restrict__ h,
             const float* __restrict__ mask,
             const float* __restrict__ trans,
             float* __restrict__ out, int T) {
  const int b = blockIdx.x;
  const int wid = threadIdx.x >> 6;
  const int lane = threadIdx.x & 63;
  const int S = T >> 1;

  const float* __restrict__ hb = h + (size_t)b * T * L;
  const float* __restrict__ mb = mask + (size_t)b * T;

  __shared__ float xq[64];
  __shared__ int xmi;

  int Mi; float rs; float st;
  if (wid == 0) st = half_pass<false>(hb, mb, trans, T, S, lane, Mi, rs);
  else          st = half_pass<true >(hb, mb, trans, T, S, lane, Mi, rs);

  if (wid == 1) {                            // publish backward result
    xq[lane] = st * rs;                      // apply pending renorm scale
    if (lane == 0) xmi = Mi;
  }
  __syncthreads();
  if (wid == 0) {                            // combine: dot + logs
    float d = (st * rs) * xq[lane];          // idle/dead lanes contribute 0
#pragma unroll
    for (int off = 32; off; off >>= 1) d += __shfl_xor(d, off, 64);
    if (lane == 0)
      out[b] = ((float)(Mi + xmi) + __log2f(d)) * LN2f;
  }
}

extern "C" void kernel_launch(void* const* d_in, const int* in_sizes, int n_in,
                              void* d_out, int out_size, void* d_ws, size_t ws_size,
                              hipStream_t stream) {
  const float* h     = (const float*)d_in[0];
  const float* mask  = (const float*)d_in[1];
  const float* trans = (const float*)d_in[2];
  float* out = (float*)d_out;
  const int B = out_size;                    // one output per chain
  const int T = in_sizes[1] / B;             // mask has B*T elements
  crf_fwd<<<B, 128, 0, stream>>>(h, mask, trans, out, T);
}

// Round 8
// 222.542 us; speedup vs baseline: 1.1337x; 1.0007x over previous
//
#include <hip/hip_runtime.h>
#include <math.h>

typedef float f32x2 __attribute__((ext_vector_type(2)));
typedef float f32x4 __attribute__((ext_vector_type(4)));

namespace {
constexpr int L = 48;
constexpr int OCT = 8;                      // time steps per prefetch window
constexpr float LN2f = 0.69314718055994530942f;
}

// Block = one chain = 4 waves: {w0,w1}=fwd pass, {w2,w3}=bwd pass.
// Each pass: 2 waves split the 48 columns; lane l<48 -> output ip=ww*24+(l>>1),
// column half jh=l&1 (24 cols each). E slice = 12 f32x2 VGPRs (stays resident,
// unlike rounds 3-5 where E[48] was spilled: VGPR_Count=44 < 48).
// State broadcast via LDS double buffer, ds_read_b128 x6 (2-way broadcast,
// conflict-free), 12 v_pk_fma_f32 + shfl_xor(1) combine. ONE sync per step.
// Deferred-shift renorm every 4 steps from the broadcast values (round-5 math,
// validated absmax 0.0).
template<bool BWD>
__device__ __forceinline__ float pass_run(
    const float* __restrict__ hb, const float* __restrict__ mb,
    const float* __restrict__ trans, int T, int S, int l, int ww,
    float (*pbuf)[64], int& Mi_out, float& rs_out) {
  const bool act = l < L;
  const int half = l & 1;                   // column half
  const int ip = act ? (ww * 24 + (l >> 1)) : 0;   // output label
  const int wi = act ? (ww * 24 + (l >> 1)) : l;   // write slot (idle->48..63)

  f32x2 Ep[12];                             // E[ip][half*24 .. +23] (fwd) / E^T (bwd)
  if (act) {
#pragma unroll
    for (int k = 0; k < 12; ++k) {
      const int j0 = half * 24 + 2 * k;
      const float e0 = __expf(trans[BWD ? ((j0 + 0) * L + ip) : (ip * L + j0 + 0)]);
      const float e1 = __expf(trans[BWD ? ((j0 + 1) * L + ip) : (ip * L + j0 + 1)]);
      Ep[k] = (f32x2){e0, e1};
    }
  } else {
#pragma unroll
    for (int k = 0; k < 12; ++k) Ep[k] = (f32x2){0.f, 0.f};
  }

  float p = BWD ? (act ? 1.0f : 0.0f)       // ones
                : ((act && ip == 1) ? 1.0f : 0.0f);  // e_BOS; e^NEG = 0
  int Mi = 0;
  float rs = 1.0f;

  const int NOCT = S / OCT;
  float hf[OCT], mf[OCT];
#pragma unroll
  for (int k = 0; k < OCT; ++k) {
    const int t = BWD ? (T - 1 - k) : k;
    hf[k] = hb[t * L + ip];
    mf[k] = mb[t];
  }

  // initial broadcast: fwd -> p0; bwd -> g_{T-1} * q0
  pbuf[0][wi] = BWD ? p * __expf(hf[0]) : p;
  __syncthreads();
  int cur = 0;

  for (int oct = 0; oct < NOCT; ++oct) {
    float hn[OCT], mn[OCT];
    if (oct + 1 < NOCT) {
#pragma unroll
      for (int k = 0; k < OCT; ++k) {
        const int s = (oct + 1) * OCT + k;
        const int t = BWD ? (T - 1 - s) : s;
        hn[k] = hb[t * L + ip];
        mn[k] = mb[t];
      }
    } else {
#pragma unroll
      for (int k = 0; k < OCT; ++k) { hn[k] = 0.f; mn[k] = 1.f; }
    }

#pragma unroll
    for (int tt = 0; tt < OCT; ++tt) {
      const bool RENORM = ((tt & 3) == 3);
      const float* src = pbuf[cur];
      const f32x4 v0 = *(const f32x4*)(src + half * 24 + 0);
      const f32x4 v1 = *(const f32x4*)(src + half * 24 + 4);
      const f32x4 v2 = *(const f32x4*)(src + half * 24 + 8);
      const f32x4 v3 = *(const f32x4*)(src + half * 24 + 12);
      const f32x4 v4 = *(const f32x4*)(src + half * 24 + 16);
      const f32x4 v5 = *(const f32x4*)(src + half * 24 + 20);

      f32x2 a0 = v0.xy * Ep[0], a1 = v0.zw * Ep[1];
      a0 += v1.xy * Ep[2];  a1 += v1.zw * Ep[3];
      a0 += v2.xy * Ep[4];  a1 += v2.zw * Ep[5];
      a0 += v3.xy * Ep[6];  a1 += v3.zw * Ep[7];
      a0 += v4.xy * Ep[8];  a1 += v4.zw * Ep[9];
      a0 += v5.xy * Ep[10]; a1 += v5.zw * Ep[11];
      const f32x2 s2 = a0 + a1;
      const float sh = s2.x + s2.y;
      const float s = sh + __shfl_xor(sh, 1, 64);   // partner column-half

      const float pn = BWD ? s : s * (__expf(hf[tt]) * rs);
      const float pr = p * rs;
      p = (mf[tt] > 0.5f) ? pn : pr;        // mask wave-uniform per (b,t)
      rs = 1.0f;

      if (RENORM) {                          // stale max from broadcast values
        f32x2 m0 = v0.xy, m1 = v0.zw;
        m0 = (f32x2){fmaxf(m0.x, v1.x), fmaxf(m0.y, v1.y)};
        m1 = (f32x2){fmaxf(m1.x, v1.z), fmaxf(m1.y, v1.w)};
        m0 = (f32x2){fmaxf(m0.x, v2.x), fmaxf(m0.y, v2.y)};
        m1 = (f32x2){fmaxf(m1.x, v2.z), fmaxf(m1.y, v2.w)};
        m0 = (f32x2){fmaxf(m0.x, v3.x), fmaxf(m0.y, v3.y)};
        m1 = (f32x2){fmaxf(m1.x, v3.z), fmaxf(m1.y, v3.w)};
        m0 = (f32x2){fmaxf(m0.x, v4.x), fmaxf(m0.y, v4.y)};
        m1 = (f32x2){fmaxf(m1.x, v4.z), fmaxf(m1.y, v4.w)};
        m0 = (f32x2){fmaxf(m0.x, v5.x), fmaxf(m0.y, v5.y)};
        m1 = (f32x2){fmaxf(m1.x, v5.z), fmaxf(m1.y, v5.w)};
        float mx = fmaxf(fmaxf(m0.x, m0.y), fmaxf(m1.x, m1.y));
        mx = fmaxf(mx, __shfl_xor(mx, 1, 64));      // other 24 columns
        const unsigned ub = __float_as_uint(mx);
        const int ke = (int)(ub >> 23);
        const bool ok = (ke > 0) && (ke < 255);
        rs = ok ? __uint_as_float((unsigned)(254 - ke) << 23) : 1.0f;
        Mi += ok ? (ke - 127) : 0;
      }

      // write broadcast for next step (bwd folds next g and pending rs)
      const float hnx = (tt < OCT - 1) ? hf[tt + 1] : hn[0];
      pbuf[cur ^ 1][wi] = BWD ? p * (__expf(hnx) * rs) : p;
      __syncthreads();
      cur ^= 1;
    }
#pragma unroll
    for (int k = 0; k < OCT; ++k) { hf[k] = hn[k]; mf[k] = mn[k]; }
  }
  Mi_out = Mi;
  rs_out = rs;                               // pending scale, apply at exit
  return p;
}

__global__ __launch_bounds__(256, 4)
void crf_fwd(const float* __restrict__ h,
             const float* __restrict__ mask,
             const float* __restrict__ trans,
             float* __restrict__ out, int T) {
  const int b = blockIdx.x;
  const int wv = threadIdx.x >> 6;
  const int l = threadIdx.x & 63;
  const int pass = wv >> 1;                  // 0 = fwd, 1 = bwd
  const int ww = wv & 1;                     // output-half within pass
  const int S = T >> 1;

  __shared__ __align__(16) float pbuf[2][2][64];   // [pass][dbuf][slot]
  __shared__ float fin[2][64];
  __shared__ int mi_sh[2];

  const float* __restrict__ hb = h + (size_t)b * T * L;
  const float* __restrict__ mb = mask + (size_t)b * T;

  int Mi; float rs; float pf;
  if (pass == 0)
    pf = pass_run<false>(hb, mb, trans, T, S, l, ww, pbuf[0], Mi, rs);
  else
    pf = pass_run<true >(hb, mb, trans, T, S, l, ww, pbuf[1], Mi, rs);

  const int ip = (l < L) ? (ww * 24 + (l >> 1)) : 0;
  if (l < L && (l & 1) == 0) fin[pass][ip] = pf * rs;
  if (ww == 0 && l == 0) mi_sh[pass] = Mi;
  __syncthreads();

  if (wv == 0) {                             // combine: dot + logs
    float d = (l < L) ? fin[0][l] * fin[1][l] : 0.0f;
#pragma unroll
    for (int off = 32; off; off >>= 1) d += __shfl_xor(d, off, 64);
    if (l == 0)
      out[b] = ((float)(mi_sh[0] + mi_sh[1]) + __log2f(d)) * LN2f;
  }
}

extern "C" void kernel_launch(void* const* d_in, const int* in_sizes, int n_in,
                              void* d_out, int out_size, void* d_ws, size_t ws_size,
                              hipStream_t stream) {
  const float* h     = (const float*)d_in[0];
  const float* mask  = (const float*)d_in[1];
  const float* trans = (const float*)d_in[2];
  float* out = (float*)d_out;
  const int B = out_size;                    // one output per chain
  const int T = in_sizes[1] / B;             // mask has B*T elements
  crf_fwd<<<B, 256, 0, stream>>>(h, mask, trans, out, T);
}

// Round 12
// 206.089 us; speedup vs baseline: 1.2242x; 1.0798x over previous
//
#include <hip/hip_runtime.h>
#include <math.h>

typedef float f32x2 __attribute__((ext_vector_type(2)));
typedef float f32x4 __attribute__((ext_vector_type(4)));

namespace {
constexpr int L = 48;
constexpr int EST = 52;   // E row stride (floats): 208B = 16B-aligned; 48 lanes
                          // spread over 8 distinct bank groups (b128 optimum)
constexpr int OCT = 8;    // time steps per h/mask prefetch window
constexpr float LN2f = 0.69314718055994530942f;
}

// Block = one chain = 2 independent waves (NO barrier in main loop):
//   wave 0 (fwd): p <- diag(e^{h_t}) E p,      t = 0..S-1,   p0 = e_BOS
//   wave 1 (bwd): r <- E^T (e^{h_t} (*) r),    t = T-1..S,   r0 = 1
//   out = ln2 * (Mi_f + Mi_b + log2(sum_i p_i r_i))
// E lives in LDS (row-major, stride 52) -> zero register pressure for E;
// rounds 2-8 all showed VGPR_Count=40 (E spilled/remat) as the real bound.
// p broadcast via wave-private LDS double buffer: 12 uniform ds_read_b128
// (hardware broadcast, conflict-free) + 12 E-row ds_read_b128 + 24 pk_fma.
// Deferred-shift renorm every 4 steps, lane-local (no shuffles): max over the
// 48 broadcast values every lane already loaded -> wave-uniform rs, Mi.
template<bool BWD>
__device__ __forceinline__ float stream_run(
    const float* __restrict__ hb, const float* __restrict__ mb,
    const float* __restrict__ Erow, float* __restrict__ pb0,
    float* __restrict__ pb1, int T, int S, int l,
    int& Mi_out, float& rs_out) {
  const bool act = l < L;
  const int sl = act ? l : 0;

  float p = BWD ? (act ? 1.0f : 0.0f)           // ones
                : ((l == 1) ? 1.0f : 0.0f);     // e_BOS; e^NEG = 0 exactly
  int Mi = 0;
  float rs = 1.0f;

  float hf[OCT], mf[OCT];
#pragma unroll
  for (int k = 0; k < OCT; ++k) {
    const int t = BWD ? (T - 1 - k) : k;
    hf[k] = hb[t * L + sl];
    mf[k] = mb[t];
  }

  // initial broadcast: fwd -> p0 ; bwd -> g_{T-1} (*) r0
  if (act) pb0[l] = BWD ? p * __expf(hf[0]) : p;
  // same-wave DS ops retire in order; compiler inserts lgkmcnt before reads

  const int NOCT = S / OCT;
  for (int oct = 0; oct < NOCT; ++oct) {
    float hn[OCT], mn[OCT];
    if (oct + 1 < NOCT) {                        // prefetch next window early
#pragma unroll
      for (int k = 0; k < OCT; ++k) {
        const int s = (oct + 1) * OCT + k;
        const int t = BWD ? (T - 1 - s) : s;
        hn[k] = hb[t * L + sl];
        mn[k] = mb[t];
      }
    } else {
#pragma unroll
      for (int k = 0; k < OCT; ++k) { hn[k] = 0.f; mn[k] = 1.f; }
    }

#pragma unroll
    for (int tt = 0; tt < OCT; ++tt) {
      const bool RN = ((tt & 3) == 3);           // compile-time (unrolled)
      const float* src = (tt & 1) ? pb1 : pb0;   // static buffer parity
      float* dst = (tt & 1) ? pb0 : pb1;
      const f32x4* s4 = (const f32x4*)src;       // uniform addr: broadcast
      const f32x4* e4 = (const f32x4*)Erow;      // per-lane row, 8 bank groups

      f32x2 a0 = {0.f, 0.f}, a1 = {0.f, 0.f};
      f32x2 a2 = {0.f, 0.f}, a3 = {0.f, 0.f};
      f32x4 mx = {0.f, 0.f, 0.f, 0.f};
#pragma unroll
      for (int c = 0; c < 12; ++c) {
        const f32x4 pv = s4[c];
        const f32x4 ev = e4[c];
        if (c & 1) { a2 += pv.xy * ev.xy; a3 += pv.zw * ev.zw; }
        else       { a0 += pv.xy * ev.xy; a1 += pv.zw * ev.zw; }
        if (RN)                                   // off the FMA dep chain
          mx = (f32x4){fmaxf(mx.x, pv.x), fmaxf(mx.y, pv.y),
                       fmaxf(mx.z, pv.z), fmaxf(mx.w, pv.w)};
      }
      const f32x2 sc = (a0 + a2) + (a1 + a3);
      const float s = sc.x + sc.y;               // full sum: no shuffle needed

      const float g = __expf(hf[tt]);
      const float pn = BWD ? s : s * (g * rs);   // fwd: apply pending rs here
      const float pr = p * rs;                   // masked carry, same scale
      p = (mf[tt] > 0.5f) ? pn : pr;             // mask wave-uniform per (b,t)
      rs = 1.0f;

      if (RN) {                                  // lane-local, wave-uniform
        const float m01 = fmaxf(mx.x, mx.y);
        const float m23 = fmaxf(mx.z, mx.w);
        const unsigned ub = __float_as_uint(fmaxf(m01, m23));
        const int ke = (int)(ub >> 23) & 0xFF;
        const bool ok = (ke > 0) && (ke < 255);
        rs = ok ? __uint_as_float((unsigned)(254 - ke) << 23) : 1.0f;
        Mi += ok ? (ke - 127) : 0;
      }

      if (act) {
        if (BWD) {                               // fold next g and fresh rs
          const float hnx = (tt < OCT - 1) ? hf[tt + 1] : hn[0];
          dst[l] = p * (__expf(hnx) * rs);
        } else {
          dst[l] = p;                            // fwd: rs applied next step
        }
      }
    }
#pragma unroll
    for (int k = 0; k < OCT; ++k) { hf[k] = hn[k]; mf[k] = mn[k]; }
  }
  Mi_out = Mi;
  rs_out = rs;                                   // pending scale: apply at exit
  return p;
}

__global__ __launch_bounds__(128, 2)
void crf_fwd(const float* __restrict__ h,
             const float* __restrict__ mask,
             const float* __restrict__ trans,
             float* __restrict__ out, int T) {
  const int b = blockIdx.x;
  const int w = threadIdx.x >> 6;                // 0 = fwd wave, 1 = bwd wave
  const int l = threadIdx.x & 63;
  const bool act = l < L;
  const int S = T >> 1;

  __shared__ __align__(16) float Elds[2][L * EST];   // ~20 KB
  __shared__ __align__(16) float pbuf[2][2][64];     // [wave][dbuf][slot]
  __shared__ float fin[64];
  __shared__ int mi_sh;

  // fill this wave's E: fwd rows E[i][j]=e^trans[i][j]; bwd rows of E^T
  float* E = Elds[w];
  if (act) {
    for (int r = 0; r < L; ++r)
      E[r * EST + l] = __expf(trans[w ? (l * L + r) : (r * L + l)]);
  }
  // each wave reads only its own E -> in-wave ordering suffices, no barrier

  const float* hb = h + (size_t)b * T * L;
  const float* mb = mask + (size_t)b * T;
  const int sl = act ? l : 0;
  const float* Erow = E + sl * EST;

  int Mi; float rs; float pf;
  if (w == 0)
    pf = stream_run<false>(hb, mb, Erow, pbuf[0][0], pbuf[0][1], T, S, l, Mi, rs);
  else
    pf = stream_run<true >(hb, mb, Erow, pbuf[1][0], pbuf[1][1], T, S, l, Mi, rs);

  if (w == 1) {                                  // publish backward result
    if (act) fin[l] = pf * rs;                   // apply pending scale
    if (l == 0) mi_sh = Mi;
  }
  __syncthreads();
  if (w == 0) {                                  // combine: dot + logs
    float d = act ? (pf * rs) * fin[l] : 0.0f;
#pragma unroll
    for (int off = 32; off; off >>= 1) d += __shfl_xor(d, off, 64);
    if (l == 0) out[b] = ((float)(Mi + mi_sh) + __log2f(d)) * LN2f;
  }
}

extern "C" void kernel_launch(void* const* d_in, const int* in_sizes, int n_in,
                              void* d_out, int out_size, void* d_ws, size_t ws_size,
                              hipStream_t stream) {
  const float* h     = (const float*)d_in[0];
  const float* mask  = (const float*)d_in[1];
  const float* trans = (const float*)d_in[2];
  float* out = (float*)d_out;
  const int B = out_size;                        // one output per chain
  const int T = in_sizes[1] / B;                 // mask has B*T elements
  crf_fwd<<<B, 128, 0, stream>>>(h, mask, trans, out, T);
}